// Round 8
// baseline (414.032 us; speedup 1.0000x reference)
//
#include <hip/hip_runtime.h>

#define NN 50000      // nodes
#define NE 800000     // edges
#define FIN 512
#define H1DIM 64
#define H2DIM 128
#define NC 10
#define NG 64
#define NRT 3125      // NN/16 row-tiles
#define SB 196        // sort-kernel blocks (<=256 CUs -> all co-resident)
#define SORT_THREADS (SB * 256)

typedef __attribute__((ext_vector_type(8))) short bf16x8;  // 8 bf16 (4 VGPRs)
typedef __attribute__((ext_vector_type(4))) float f32x4;

__device__ inline short f2bf(float f) {
  unsigned u = __float_as_uint(f);
  unsigned r = u + 0x7fffu + ((u >> 16) & 1u);  // RNE
  return (short)(r >> 16);
}
__device__ inline float bf2f(short s) {
  return __uint_as_float(((unsigned)(unsigned short)s) << 16);
}

// ---------------------------------------------------------------------------
// device-wide barrier: SB blocks all co-resident (SB <= 256 CUs), so spin is
// deadlock-free. Counter in global ws, zeroed by the memset each call.
// ---------------------------------------------------------------------------
__device__ __forceinline__ void gbar(int* bar, int id) {
  __syncthreads();
  if (threadIdx.x == 0) {
    __threadfence();
    atomicAdd(&bar[id], 1);
    while (atomicAdd(&bar[id], 0) < SB) {}
  }
  __syncthreads();
}

// ---------------------------------------------------------------------------
// fused counting sort: zero -> hist -> block scan -> global fixup -> scatter
// all in one dispatch. Cross-block data reads use atomic loads (stale-L1 safe
// per G16); zeroing slice is shifted so no block re-reads its own zeroed line.
// ---------------------------------------------------------------------------
__global__ __launch_bounds__(256) void sort_kernel(
    const int* __restrict__ src, const int* __restrict__ dst,
    int* __restrict__ cnt, int* __restrict__ rowptr, int* __restrict__ cursor,
    int* __restrict__ bsum, int* __restrict__ ssrc, int* __restrict__ bar) {
  const int b = blockIdx.x;
  const int t = threadIdx.x;
  const int idx = b * 256 + t;
  __shared__ int s[256];

  // P0: zero cnt (shifted slice: this block won't re-read these lines in P2)
  {
    int i = ((b + 98) % SB) * 256 + t;
    if (i < NN) cnt[i] = 0;
  }
  gbar(bar, 0);

  // P1: histogram of dst
  for (int j = idx; j < NE / 4; j += SORT_THREADS) {
    int4 d = *(const int4*)(dst + j * 4);
    atomicAdd(&cnt[d.x], 1);
    atomicAdd(&cnt[d.y], 1);
    atomicAdd(&cnt[d.z], 1);
    atomicAdd(&cnt[d.w], 1);
  }
  gbar(bar, 1);

  // P2: block-local exclusive scan of this block's cnt slice
  int v = (idx < NN) ? atomicAdd(&cnt[idx], 0) : 0;  // atomic load: L1-safe
  s[t] = v;
  __syncthreads();
  for (int off = 1; off < 256; off <<= 1) {
    int u = (t >= off) ? s[t - off] : 0;
    __syncthreads();
    s[t] += u;
    __syncthreads();
  }
  if (idx < NN) rowptr[idx] = s[t] - v;  // local exclusive
  if (t == 255) bsum[b] = s[255];
  gbar(bar, 2);

  // P3: every block redundantly scans bsum; fix rowptr, init cursor
  int bv = (t < SB) ? atomicAdd(&bsum[t], 0) : 0;  // atomic load: L1-safe
  s[t] = bv;
  __syncthreads();
  for (int off = 1; off < 256; off <<= 1) {
    int u = (t >= off) ? s[t - off] : 0;
    __syncthreads();
    s[t] += u;
    __syncthreads();
  }
  int prefix = (b == 0) ? 0 : s[b - 1];
  if (idx < NN) {
    int p = rowptr[idx] + prefix;   // rowptr[idx]: own write, own L1 = correct
    rowptr[idx] = p;
    cursor[idx] = p;
  }
  if (idx == 0) rowptr[NN] = NE;
  gbar(bar, 3);

  // P4: scatter src into dst-grouped order
  for (int j = idx; j < NE / 4; j += SORT_THREADS) {
    int4 sv = *(const int4*)(src + j * 4);
    int4 dv = *(const int4*)(dst + j * 4);
    int p0 = atomicAdd(&cursor[dv.x], 1); ssrc[p0] = sv.x;
    int p1 = atomicAdd(&cursor[dv.y], 1); ssrc[p1] = sv.y;
    int p2 = atomicAdd(&cursor[dv.z], 1); ssrc[p2] = sv.z;
    int p3 = atomicAdd(&cursor[dv.w], 1); ssrc[p3] = sv.w;
  }
}

// ---------------------------------------------------------------------------
// wbtf: [w1_l | w1_r] -> bf16 B-frag order.  131 KB, L2-resident.
// ---------------------------------------------------------------------------
__global__ __launch_bounds__(256) void wbtf_prep_kernel(
    const float* __restrict__ wl, const float* __restrict__ wr,
    short* __restrict__ wbtf) {
  int w = blockIdx.x * 4 + (threadIdx.x >> 6);   // 0..127 = ni*16+ks
  int lane = threadIdx.x & 63;
  int ni = w >> 4;
  int ks = w & 15;
  int n = ni * 16 + (lane & 15);
  int k = ks * 32 + (lane >> 4) * 8;
  bf16x8 o;
#pragma unroll
  for (int j = 0; j < 8; j++) {
    float v = (n < 64) ? wl[(size_t)(k + j) * 64 + n]
                       : wr[(size_t)(k + j) * 64 + (n - 64)];
    o[j] = f2bf(v);
  }
  *(bf16x8*)(wbtf + ((size_t)w * 64 + lane) * 8) = o;
}

// ---------------------------------------------------------------------------
// GEMM1 fused with x->bf16 conversion. LDS-free, barrier-free.
// One wave = 16 rows x 128 cols; A loaded straight from x (f32) in frag
// order (per instr: 16 rows x contiguous segments), converted in-register.
// 3125 waves (~3/SIMD) hide load latency via TLP + ping-pong prefetch.
// ---------------------------------------------------------------------------
__global__ __launch_bounds__(256) void gemm1_kernel(
    const float* __restrict__ x, const short* __restrict__ wbtf,
    short* __restrict__ xwl, float* __restrict__ xwr) {
  int w = blockIdx.x * 4 + (threadIdx.x >> 6);   // row-tile id
  if (w >= NRT) return;
  int lane = threadIdx.x & 63;
  int l15 = lane & 15;
  int q = lane >> 4;
  const float* px = x + (size_t)(w * 16 + l15) * FIN + q * 8;  // + ks*32
  const short* pb = wbtf + (size_t)lane * 8;                   // + ni*8192 + ks*512

  const f32x4 z = {0.f, 0.f, 0.f, 0.f};
  f32x4 acc[8];
#pragma unroll
  for (int ni = 0; ni < 8; ni++) acc[ni] = z;

  float4 av0, av1, nv0, nv1;
  bf16x8 B0[8], B1[8];
  av0 = *(const float4*)(px);
  av1 = *(const float4*)(px + 4);
#pragma unroll
  for (int ni = 0; ni < 8; ni++)
    B0[ni] = *(const bf16x8*)(pb + (size_t)ni * 8192);

#pragma unroll
  for (int ks = 0; ks < 16; ks += 2) {
    if (ks + 1 < 16) {
      nv0 = *(const float4*)(px + (ks + 1) * 32);
      nv1 = *(const float4*)(px + (ks + 1) * 32 + 4);
#pragma unroll
      for (int ni = 0; ni < 8; ni++)
        B1[ni] = *(const bf16x8*)(pb + (size_t)ni * 8192 + (ks + 1) * 512);
    }
    {
      bf16x8 af;
      af[0] = f2bf(av0.x); af[1] = f2bf(av0.y);
      af[2] = f2bf(av0.z); af[3] = f2bf(av0.w);
      af[4] = f2bf(av1.x); af[5] = f2bf(av1.y);
      af[6] = f2bf(av1.z); af[7] = f2bf(av1.w);
#pragma unroll
      for (int ni = 0; ni < 8; ni++)
        acc[ni] = __builtin_amdgcn_mfma_f32_16x16x32_bf16(af, B0[ni], acc[ni], 0, 0, 0);
    }
    if (ks + 2 < 16) {
      av0 = *(const float4*)(px + (ks + 2) * 32);
      av1 = *(const float4*)(px + (ks + 2) * 32 + 4);
#pragma unroll
      for (int ni = 0; ni < 8; ni++)
        B0[ni] = *(const bf16x8*)(pb + (size_t)ni * 8192 + (ks + 2) * 512);
    }
    {
      bf16x8 af;
      af[0] = f2bf(nv0.x); af[1] = f2bf(nv0.y);
      af[2] = f2bf(nv0.z); af[3] = f2bf(nv0.w);
      af[4] = f2bf(nv1.x); af[5] = f2bf(nv1.y);
      af[6] = f2bf(nv1.z); af[7] = f2bf(nv1.w);
#pragma unroll
      for (int ni = 0; ni < 8; ni++)
        acc[ni] = __builtin_amdgcn_mfma_f32_16x16x32_bf16(af, B1[ni], acc[ni], 0, 0, 0);
    }
  }

  // epilogue: col = ni*16 + l15; row = w*16 + q*4 + r
  int row_base = w * 16 + q * 4;
#pragma unroll
  for (int ni = 0; ni < 8; ni++) {
    int col = ni * 16 + l15;
    int c = col & 63;
#pragma unroll
    for (int r = 0; r < 4; r++) {
      int row = row_base + r;
      if (col < 64) xwl[(size_t)row * 64 + c] = f2bf(acc[ni][r]);
      else          xwr[(size_t)row * 64 + c] = acc[ni][r];
    }
  }
}

// ---------------------------------------------------------------------------
// agg1 + h1: h1[i] = relu(mean_{s in N(i)} xwl[s] + b1 + xwr[i])  (bf16 out)
// one wave per node; 8 chunk-lanes x 8 edge-slots, 16B gathers
// ---------------------------------------------------------------------------
__global__ __launch_bounds__(256) void agg1_h1_kernel(
    const int* __restrict__ rowptr, const int* __restrict__ ssrc,
    const short* __restrict__ xwl, const float* __restrict__ xwr,
    const float* __restrict__ b1, short* __restrict__ h1) {
  int node = blockIdx.x * 4 + (threadIdx.x >> 6);
  if (node >= NN) return;
  int lane = threadIdx.x & 63;
  int c = lane & 7;        // feature chunk (8 bf16 = 16 B)
  int r = lane >> 3;       // edge slot 0..7
  int lo = rowptr[node], hi = rowptr[node + 1];
  float acc[8];
#pragma unroll
  for (int k = 0; k < 8; k++) acc[k] = 0.f;
  for (int e = lo + r; e < hi; e += 8) {
    int s = ssrc[e];
    bf16x8 v = *(const bf16x8*)(xwl + (size_t)s * 64 + c * 8);
#pragma unroll
    for (int k = 0; k < 8; k++) acc[k] += bf2f(v[k]);
  }
#pragma unroll
  for (int k = 0; k < 8; k++) {
    acc[k] += __shfl_xor(acc[k], 8);
    acc[k] += __shfl_xor(acc[k], 16);
    acc[k] += __shfl_xor(acc[k], 32);
  }
  if (r == 0) {
    float dg = fmaxf((float)(hi - lo), 1.0f);
    const float* xr = xwr + (size_t)node * 64 + c * 8;
    bf16x8 out;
#pragma unroll
    for (int k = 0; k < 8; k++) {
      float v = fmaxf(acc[k] / dg + b1[c * 8 + k] + xr[k], 0.f);
      out[k] = f2bf(v);
    }
    *(bf16x8*)(h1 + (size_t)node * 64 + c * 8) = out;
  }
}

// ---------------------------------------------------------------------------
// agg2: agg2[i] = sum_{s in N(i)} h1[s]   (f32 out, per-node — NO atomics)
// ---------------------------------------------------------------------------
__global__ __launch_bounds__(256) void agg2_kernel(
    const int* __restrict__ rowptr, const int* __restrict__ ssrc,
    const short* __restrict__ h1, float* __restrict__ agg2) {
  int node = blockIdx.x * 4 + (threadIdx.x >> 6);
  if (node >= NN) return;
  int lane = threadIdx.x & 63;
  int c = lane & 7;
  int r = lane >> 3;
  int lo = rowptr[node], hi = rowptr[node + 1];
  float acc[8];
#pragma unroll
  for (int k = 0; k < 8; k++) acc[k] = 0.f;
  for (int e = lo + r; e < hi; e += 8) {
    int s = ssrc[e];
    bf16x8 v = *(const bf16x8*)(h1 + (size_t)s * 64 + c * 8);
#pragma unroll
    for (int k = 0; k < 8; k++) acc[k] += bf2f(v[k]);
  }
#pragma unroll
  for (int k = 0; k < 8; k++) {
    acc[k] += __shfl_xor(acc[k], 8);
    acc[k] += __shfl_xor(acc[k], 16);
    acc[k] += __shfl_xor(acc[k], 32);
  }
  if (r == 0) {
    float* p = agg2 + (size_t)node * 64 + c * 8;
    f32x4 lo4 = {acc[0], acc[1], acc[2], acc[3]};
    f32x4 hi4 = {acc[4], acc[5], acc[6], acc[7]};
    *(f32x4*)(p) = lo4;
    *(f32x4*)(p + 4) = hi4;
  }
}

// ---------------------------------------------------------------------------
// pool phase1: run-length accumulate (batch sorted) + sparse atomic flush
// ---------------------------------------------------------------------------
__global__ __launch_bounds__(256) void pool1_kernel(
    const int* __restrict__ batch, const float* __restrict__ agg2,
    const short* __restrict__ h1, const int* __restrict__ rowptr,
    float* __restrict__ poolA, float* __restrict__ poolB,
    float* __restrict__ poolCnt) {
  int t = threadIdx.x;
  int c = t & 15;
  int s = t >> 4;
  int n0 = blockIdx.x * 256 + s * 16;
  int n1 = n0 + 16;
  if (n1 > NN) n1 = NN;

  f32x4 aA = {0.f, 0.f, 0.f, 0.f};
  f32x4 aB = {0.f, 0.f, 0.f, 0.f};
  int cur_g = -1;
  float run = 0.f;
  for (int n = n0; n < n1; n++) {
    int g = batch[n];
    if (g != cur_g) {
      if (cur_g >= 0) {
        float* pa = poolA + (size_t)cur_g * 64 + c * 4;
        float* pb = poolB + (size_t)cur_g * 64 + c * 4;
#pragma unroll
        for (int k = 0; k < 4; k++) {
          atomicAdd(&pa[k], aA[k]);
          atomicAdd(&pb[k], aB[k]);
        }
        if (c == 0) atomicAdd(&poolCnt[cur_g], run);
      }
      cur_g = g;
      aA = (f32x4){0.f, 0.f, 0.f, 0.f};
      aB = (f32x4){0.f, 0.f, 0.f, 0.f};
      run = 0.f;
    }
    float rd = 1.0f / fmaxf((float)(rowptr[n + 1] - rowptr[n]), 1.0f);
    f32x4 a2 = *(const f32x4*)(agg2 + (size_t)n * 64 + c * 4);
    const short* hp = h1 + (size_t)n * 64 + c * 4;
#pragma unroll
    for (int k = 0; k < 4; k++) {
      aA[k] = fmaf(a2[k], rd, aA[k]);
      aB[k] += bf2f(hp[k]);
    }
    run += 1.f;
  }
  if (cur_g >= 0) {
    float* pa = poolA + (size_t)cur_g * 64 + c * 4;
    float* pb = poolB + (size_t)cur_g * 64 + c * 4;
#pragma unroll
    for (int k = 0; k < 4; k++) {
      atomicAdd(&pa[k], aA[k]);
      atomicAdd(&pb[k], aB[k]);
    }
    if (c == 0) atomicAdd(&poolCnt[cur_g], run);
  }
}

// ---------------------------------------------------------------------------
// final: pooled = (poolA/cnt)@w2l + (poolB/cnt)@w2r + b2 ; @wfc + bfc ;
// log_softmax. One block per graph.
// ---------------------------------------------------------------------------
__global__ __launch_bounds__(128) void final_kernel(
    const float* __restrict__ poolA, const float* __restrict__ poolB,
    const float* __restrict__ poolCnt, const float* __restrict__ w2l,
    const float* __restrict__ w2r, const float* __restrict__ b2,
    const float* __restrict__ wfc, const float* __restrict__ bfc,
    float* __restrict__ out) {
  int g = blockIdx.x;
  int j = threadIdx.x;
  __shared__ float sp[H2DIM];
  __shared__ float sl[NC];

  float invc = 1.0f / fmaxf(poolCnt[g], 1.0f);
  float v = b2[j];
  for (int k = 0; k < 64; k++) {
    float a = poolA[g * 64 + k] * invc;
    float b = poolB[g * 64 + k] * invc;
    v = fmaf(a, w2l[k * 128 + j], v);
    v = fmaf(b, w2r[k * 128 + j], v);
  }
  sp[j] = v;
  __syncthreads();
  if (j < NC) {
    float lg = bfc[j];
    for (int k = 0; k < H2DIM; k++) lg = fmaf(sp[k], wfc[k * NC + j], lg);
    sl[j] = lg;
  }
  __syncthreads();
  if (j < NC) {
    float m = -1e30f;
    for (int k = 0; k < NC; k++) m = fmaxf(m, sl[k]);
    float s = 0.f;
    for (int k = 0; k < NC; k++) s += expf(sl[k] - m);
    out[g * NC + j] = sl[j] - m - logf(s);
  }
}

extern "C" void kernel_launch(void* const* d_in, const int* in_sizes, int n_in,
                              void* d_out, int out_size, void* d_ws,
                              size_t ws_size, hipStream_t stream) {
  const float* x   = (const float*)d_in[0];
  const int* edge  = (const int*)d_in[1];
  const int* batch = (const int*)d_in[2];
  const float* w1l = (const float*)d_in[3];
  const float* b1l = (const float*)d_in[4];
  const float* w1r = (const float*)d_in[5];
  const float* w2l = (const float*)d_in[6];
  const float* b2l = (const float*)d_in[7];
  const float* w2r = (const float*)d_in[8];
  const float* wfc = (const float*)d_in[9];
  const float* bfc = (const float*)d_in[10];
  float* out = (float*)d_out;

  const int* src = edge;
  const int* dst = edge + NE;

  const size_t NF = (size_t)NN * 64;
  // zeroed region: bar[8] + poolA[4096] + poolB[4096] + poolCnt[64]
  int*   bar     = (int*)d_ws;
  float* poolA   = (float*)(bar + 8);
  float* poolB   = poolA + (size_t)NG * 64;
  float* poolCnt = poolB + (size_t)NG * 64;
  int*   cnt     = (int*)(poolCnt + NG);
  int*   cursor  = cnt + NN;
  int*   rowptr  = cursor + NN;            // [NN+1] padded to 50004
  int*   bsum    = rowptr + 50004;         // [256]
  int*   ssrc    = bsum + 256;             // [NE]
  short* xwl     = (short*)(ssrc + NE);    // bf16 [NN][64]
  short* h1s     = xwl + NF;               // bf16 [NN][64]
  short* wbtf    = h1s + NF;               // bf16 frag-major [128][512]
  float* xwr     = (float*)(wbtf + 65536); // f32  [NN][64]
  float* agg2    = xwr + NF;               // f32  [NN][64]

  hipMemsetAsync(bar, 0, (8 + 2 * NG * 64 + NG) * sizeof(int), stream);

  wbtf_prep_kernel<<<32, 256, 0, stream>>>(w1l, w1r, wbtf);
  sort_kernel<<<SB, 256, 0, stream>>>(src, dst, cnt, rowptr, cursor, bsum, ssrc, bar);
  gemm1_kernel<<<(NRT + 3) / 4, 256, 0, stream>>>(x, wbtf, xwl, xwr);

  agg1_h1_kernel<<<(NN + 3) / 4, 256, 0, stream>>>(rowptr, ssrc, xwl, xwr, b1l, h1s);
  agg2_kernel<<<(NN + 3) / 4, 256, 0, stream>>>(rowptr, ssrc, h1s, agg2);
  pool1_kernel<<<SB, 256, 0, stream>>>(batch, agg2, h1s, rowptr, poolA, poolB, poolCnt);
  final_kernel<<<NG, 128, 0, stream>>>(poolA, poolB, poolCnt, w2l, w2r, b2l, wfc, bfc, out);
}

// Round 9
// 381.006 us; speedup vs baseline: 1.0867x; 1.0867x over previous
//
#include <hip/hip_runtime.h>

#define NN 50000      // nodes
#define NE 800000     // edges
#define FIN 512
#define H1DIM 64
#define H2DIM 128
#define NC 10
#define NG 64
#define NRT 3125      // NN/16 row-tiles
#define SCAN_BLOCKS 196   // ceil(50000/256)

typedef __attribute__((ext_vector_type(8))) short bf16x8;  // 8 bf16 (4 VGPRs)
typedef __attribute__((ext_vector_type(4))) float f32x4;

__device__ inline short f2bf(float f) {
  unsigned u = __float_as_uint(f);
  unsigned r = u + 0x7fffu + ((u >> 16) & 1u);  // RNE
  return (short)(r >> 16);
}
__device__ inline float bf2f(short s) {
  return __uint_as_float(((unsigned)(unsigned short)s) << 16);
}

// ---------------------------------------------------------------------------
// counting sort, split chain (max parallelism on heavy phases):
// hist(782 blk) -> scan1(196) -> scan23(196, merged) -> scatter(782)
// ---------------------------------------------------------------------------
__global__ __launch_bounds__(256) void hist_kernel(const int* __restrict__ dst,
                                                   int* __restrict__ cnt) {
  int i = (blockIdx.x * 256 + threadIdx.x) * 4;
  if (i < NE) {
    int4 d = *(const int4*)(dst + i);
    atomicAdd(&cnt[d.x], 1);
    atomicAdd(&cnt[d.y], 1);
    atomicAdd(&cnt[d.z], 1);
    atomicAdd(&cnt[d.w], 1);
  }
}

__global__ __launch_bounds__(256) void scan1_kernel(const int* __restrict__ cnt,
                                                    int* __restrict__ excl,
                                                    int* __restrict__ bsum) {
  __shared__ int s[256];
  int t = threadIdx.x;
  int i = blockIdx.x * 256 + t;
  int v = (i < NN) ? cnt[i] : 0;
  s[t] = v;
  __syncthreads();
  for (int off = 1; off < 256; off <<= 1) {
    int u = (t >= off) ? s[t - off] : 0;
    __syncthreads();
    s[t] += u;
    __syncthreads();
  }
  if (i < NN) excl[i] = s[t] - v;       // exclusive within block
  if (t == 255) bsum[blockIdx.x] = s[255];
}

// merged scan2+scan3: every block redundantly scans bsum in LDS, then fixes
// its rowptr slice and inits cursor.
__global__ __launch_bounds__(256) void scan23_kernel(const int* __restrict__ bsum,
                                                     int* __restrict__ rowptr,
                                                     int* __restrict__ cursor) {
  __shared__ int s[256];
  int t = threadIdx.x;
  int b = blockIdx.x;
  int v = (t < SCAN_BLOCKS) ? bsum[t] : 0;
  s[t] = v;
  __syncthreads();
  for (int off = 1; off < 256; off <<= 1) {
    int u = (t >= off) ? s[t - off] : 0;
    __syncthreads();
    s[t] += u;
    __syncthreads();
  }
  int prefix = (b == 0) ? 0 : s[b - 1];
  int i = b * 256 + t;
  if (i < NN) {
    int p = rowptr[i] + prefix;
    rowptr[i] = p;
    cursor[i] = p;
  }
  if (i == 0) rowptr[NN] = NE;
}

__global__ __launch_bounds__(256) void scatter_kernel(
    const int* __restrict__ src, const int* __restrict__ dst,
    int* __restrict__ cursor, int* __restrict__ ssrc) {
  int i = (blockIdx.x * 256 + threadIdx.x) * 4;
  if (i < NE) {
    int4 s = *(const int4*)(src + i);
    int4 d = *(const int4*)(dst + i);
    int p0 = atomicAdd(&cursor[d.x], 1); ssrc[p0] = s.x;
    int p1 = atomicAdd(&cursor[d.y], 1); ssrc[p1] = s.y;
    int p2 = atomicAdd(&cursor[d.z], 1); ssrc[p2] = s.z;
    int p3 = atomicAdd(&cursor[d.w], 1); ssrc[p3] = s.w;
  }
}

// ---------------------------------------------------------------------------
// wbtf: [w1_l | w1_r] -> bf16 B-frag order.  131 KB, L2-resident.
// ---------------------------------------------------------------------------
__global__ __launch_bounds__(256) void wbtf_prep_kernel(
    const float* __restrict__ wl, const float* __restrict__ wr,
    short* __restrict__ wbtf) {
  int w = blockIdx.x * 4 + (threadIdx.x >> 6);   // 0..127 = ni*16+ks
  int lane = threadIdx.x & 63;
  int ni = w >> 4;
  int ks = w & 15;
  int n = ni * 16 + (lane & 15);
  int k = ks * 32 + (lane >> 4) * 8;
  bf16x8 o;
#pragma unroll
  for (int j = 0; j < 8; j++) {
    float v = (n < 64) ? wl[(size_t)(k + j) * 64 + n]
                       : wr[(size_t)(k + j) * 64 + (n - 64)];
    o[j] = f2bf(v);
  }
  *(bf16x8*)(wbtf + ((size_t)w * 64 + lane) * 8) = o;
}

// ---------------------------------------------------------------------------
// GEMM1 fused with x->bf16 conversion. LDS-free, barrier-free.
// One wave = 16 rows x 128 cols; A loaded straight from x (f32) in frag
// order, converted in-register. Ping-pong prefetch; TLP hides latency.
// ---------------------------------------------------------------------------
__global__ __launch_bounds__(256) void gemm1_kernel(
    const float* __restrict__ x, const short* __restrict__ wbtf,
    short* __restrict__ xwl, float* __restrict__ xwr) {
  int w = blockIdx.x * 4 + (threadIdx.x >> 6);   // row-tile id
  if (w >= NRT) return;
  int lane = threadIdx.x & 63;
  int l15 = lane & 15;
  int q = lane >> 4;
  const float* px = x + (size_t)(w * 16 + l15) * FIN + q * 8;  // + ks*32
  const short* pb = wbtf + (size_t)lane * 8;                   // + ni*8192 + ks*512

  const f32x4 z = {0.f, 0.f, 0.f, 0.f};
  f32x4 acc[8];
#pragma unroll
  for (int ni = 0; ni < 8; ni++) acc[ni] = z;

  float4 av0, av1, nv0, nv1;
  bf16x8 B0[8], B1[8];
  av0 = *(const float4*)(px);
  av1 = *(const float4*)(px + 4);
#pragma unroll
  for (int ni = 0; ni < 8; ni++)
    B0[ni] = *(const bf16x8*)(pb + (size_t)ni * 8192);

#pragma unroll
  for (int ks = 0; ks < 16; ks += 2) {
    if (ks + 1 < 16) {
      nv0 = *(const float4*)(px + (ks + 1) * 32);
      nv1 = *(const float4*)(px + (ks + 1) * 32 + 4);
#pragma unroll
      for (int ni = 0; ni < 8; ni++)
        B1[ni] = *(const bf16x8*)(pb + (size_t)ni * 8192 + (ks + 1) * 512);
    }
    {
      bf16x8 af;
      af[0] = f2bf(av0.x); af[1] = f2bf(av0.y);
      af[2] = f2bf(av0.z); af[3] = f2bf(av0.w);
      af[4] = f2bf(av1.x); af[5] = f2bf(av1.y);
      af[6] = f2bf(av1.z); af[7] = f2bf(av1.w);
#pragma unroll
      for (int ni = 0; ni < 8; ni++)
        acc[ni] = __builtin_amdgcn_mfma_f32_16x16x32_bf16(af, B0[ni], acc[ni], 0, 0, 0);
    }
    if (ks + 2 < 16) {
      av0 = *(const float4*)(px + (ks + 2) * 32);
      av1 = *(const float4*)(px + (ks + 2) * 32 + 4);
#pragma unroll
      for (int ni = 0; ni < 8; ni++)
        B0[ni] = *(const bf16x8*)(pb + (size_t)ni * 8192 + (ks + 2) * 512);
    }
    {
      bf16x8 af;
      af[0] = f2bf(nv0.x); af[1] = f2bf(nv0.y);
      af[2] = f2bf(nv0.z); af[3] = f2bf(nv0.w);
      af[4] = f2bf(nv1.x); af[5] = f2bf(nv1.y);
      af[6] = f2bf(nv1.z); af[7] = f2bf(nv1.w);
#pragma unroll
      for (int ni = 0; ni < 8; ni++)
        acc[ni] = __builtin_amdgcn_mfma_f32_16x16x32_bf16(af, B1[ni], acc[ni], 0, 0, 0);
    }
  }

  // epilogue: col = ni*16 + l15; row = w*16 + q*4 + r
  int row_base = w * 16 + q * 4;
#pragma unroll
  for (int ni = 0; ni < 8; ni++) {
    int col = ni * 16 + l15;
    int c = col & 63;
#pragma unroll
    for (int r = 0; r < 4; r++) {
      int row = row_base + r;
      if (col < 64) xwl[(size_t)row * 64 + c] = f2bf(acc[ni][r]);
      else          xwr[(size_t)row * 64 + c] = acc[ni][r];
    }
  }
}

// ---------------------------------------------------------------------------
// agg1 + h1: h1[i] = relu(mean_{s in N(i)} xwl[s] + b1 + xwr[i])  (bf16 out)
// one wave per node; 8 chunk-lanes x 8 edge-slots, 16B gathers
// ---------------------------------------------------------------------------
__global__ __launch_bounds__(256) void agg1_h1_kernel(
    const int* __restrict__ rowptr, const int* __restrict__ ssrc,
    const short* __restrict__ xwl, const float* __restrict__ xwr,
    const float* __restrict__ b1, short* __restrict__ h1) {
  int node = blockIdx.x * 4 + (threadIdx.x >> 6);
  if (node >= NN) return;
  int lane = threadIdx.x & 63;
  int c = lane & 7;        // feature chunk (8 bf16 = 16 B)
  int r = lane >> 3;       // edge slot 0..7
  int lo = rowptr[node], hi = rowptr[node + 1];
  float acc[8];
#pragma unroll
  for (int k = 0; k < 8; k++) acc[k] = 0.f;
  for (int e = lo + r; e < hi; e += 8) {
    int s = ssrc[e];
    bf16x8 v = *(const bf16x8*)(xwl + (size_t)s * 64 + c * 8);
#pragma unroll
    for (int k = 0; k < 8; k++) acc[k] += bf2f(v[k]);
  }
#pragma unroll
  for (int k = 0; k < 8; k++) {
    acc[k] += __shfl_xor(acc[k], 8);
    acc[k] += __shfl_xor(acc[k], 16);
    acc[k] += __shfl_xor(acc[k], 32);
  }
  if (r == 0) {
    float dg = fmaxf((float)(hi - lo), 1.0f);
    const float* xr = xwr + (size_t)node * 64 + c * 8;
    bf16x8 out;
#pragma unroll
    for (int k = 0; k < 8; k++) {
      float v = fmaxf(acc[k] / dg + b1[c * 8 + k] + xr[k], 0.f);
      out[k] = f2bf(v);
    }
    *(bf16x8*)(h1 + (size_t)node * 64 + c * 8) = out;
  }
}

// ---------------------------------------------------------------------------
// agg2: agg2[i] = sum_{s in N(i)} h1[s]   (f32 out, per-node — NO atomics)
// ---------------------------------------------------------------------------
__global__ __launch_bounds__(256) void agg2_kernel(
    const int* __restrict__ rowptr, const int* __restrict__ ssrc,
    const short* __restrict__ h1, float* __restrict__ agg2) {
  int node = blockIdx.x * 4 + (threadIdx.x >> 6);
  if (node >= NN) return;
  int lane = threadIdx.x & 63;
  int c = lane & 7;
  int r = lane >> 3;
  int lo = rowptr[node], hi = rowptr[node + 1];
  float acc[8];
#pragma unroll
  for (int k = 0; k < 8; k++) acc[k] = 0.f;
  for (int e = lo + r; e < hi; e += 8) {
    int s = ssrc[e];
    bf16x8 v = *(const bf16x8*)(h1 + (size_t)s * 64 + c * 8);
#pragma unroll
    for (int k = 0; k < 8; k++) acc[k] += bf2f(v[k]);
  }
#pragma unroll
  for (int k = 0; k < 8; k++) {
    acc[k] += __shfl_xor(acc[k], 8);
    acc[k] += __shfl_xor(acc[k], 16);
    acc[k] += __shfl_xor(acc[k], 32);
  }
  if (r == 0) {
    float* p = agg2 + (size_t)node * 64 + c * 8;
    f32x4 lo4 = {acc[0], acc[1], acc[2], acc[3]};
    f32x4 hi4 = {acc[4], acc[5], acc[6], acc[7]};
    *(f32x4*)(p) = lo4;
    *(f32x4*)(p + 4) = hi4;
  }
}

// ---------------------------------------------------------------------------
// pool phase1: run-length accumulate (batch sorted) + sparse atomic flush
// ---------------------------------------------------------------------------
__global__ __launch_bounds__(256) void pool1_kernel(
    const int* __restrict__ batch, const float* __restrict__ agg2,
    const short* __restrict__ h1, const int* __restrict__ rowptr,
    float* __restrict__ poolA, float* __restrict__ poolB,
    float* __restrict__ poolCnt) {
  int t = threadIdx.x;
  int c = t & 15;
  int s = t >> 4;
  int n0 = blockIdx.x * 256 + s * 16;
  int n1 = n0 + 16;
  if (n1 > NN) n1 = NN;

  f32x4 aA = {0.f, 0.f, 0.f, 0.f};
  f32x4 aB = {0.f, 0.f, 0.f, 0.f};
  int cur_g = -1;
  float run = 0.f;
  for (int n = n0; n < n1; n++) {
    int g = batch[n];
    if (g != cur_g) {
      if (cur_g >= 0) {
        float* pa = poolA + (size_t)cur_g * 64 + c * 4;
        float* pb = poolB + (size_t)cur_g * 64 + c * 4;
#pragma unroll
        for (int k = 0; k < 4; k++) {
          atomicAdd(&pa[k], aA[k]);
          atomicAdd(&pb[k], aB[k]);
        }
        if (c == 0) atomicAdd(&poolCnt[cur_g], run);
      }
      cur_g = g;
      aA = (f32x4){0.f, 0.f, 0.f, 0.f};
      aB = (f32x4){0.f, 0.f, 0.f, 0.f};
      run = 0.f;
    }
    float rd = 1.0f / fmaxf((float)(rowptr[n + 1] - rowptr[n]), 1.0f);
    f32x4 a2 = *(const f32x4*)(agg2 + (size_t)n * 64 + c * 4);
    const short* hp = h1 + (size_t)n * 64 + c * 4;
#pragma unroll
    for (int k = 0; k < 4; k++) {
      aA[k] = fmaf(a2[k], rd, aA[k]);
      aB[k] += bf2f(hp[k]);
    }
    run += 1.f;
  }
  if (cur_g >= 0) {
    float* pa = poolA + (size_t)cur_g * 64 + c * 4;
    float* pb = poolB + (size_t)cur_g * 64 + c * 4;
#pragma unroll
    for (int k = 0; k < 4; k++) {
      atomicAdd(&pa[k], aA[k]);
      atomicAdd(&pb[k], aB[k]);
    }
    if (c == 0) atomicAdd(&poolCnt[cur_g], run);
  }
}

// ---------------------------------------------------------------------------
// final: pooled = (poolA/cnt)@w2l + (poolB/cnt)@w2r + b2 ; @wfc + bfc ;
// log_softmax. One block per graph.
// ---------------------------------------------------------------------------
__global__ __launch_bounds__(128) void final_kernel(
    const float* __restrict__ poolA, const float* __restrict__ poolB,
    const float* __restrict__ poolCnt, const float* __restrict__ w2l,
    const float* __restrict__ w2r, const float* __restrict__ b2,
    const float* __restrict__ wfc, const float* __restrict__ bfc,
    float* __restrict__ out) {
  int g = blockIdx.x;
  int j = threadIdx.x;
  __shared__ float sp[H2DIM];
  __shared__ float sl[NC];

  float invc = 1.0f / fmaxf(poolCnt[g], 1.0f);
  float v = b2[j];
  for (int k = 0; k < 64; k++) {
    float a = poolA[g * 64 + k] * invc;
    float b = poolB[g * 64 + k] * invc;
    v = fmaf(a, w2l[k * 128 + j], v);
    v = fmaf(b, w2r[k * 128 + j], v);
  }
  sp[j] = v;
  __syncthreads();
  if (j < NC) {
    float lg = bfc[j];
    for (int k = 0; k < H2DIM; k++) lg = fmaf(sp[k], wfc[k * NC + j], lg);
    sl[j] = lg;
  }
  __syncthreads();
  if (j < NC) {
    float m = -1e30f;
    for (int k = 0; k < NC; k++) m = fmaxf(m, sl[k]);
    float s = 0.f;
    for (int k = 0; k < NC; k++) s += expf(sl[k] - m);
    out[g * NC + j] = sl[j] - m - logf(s);
  }
}

extern "C" void kernel_launch(void* const* d_in, const int* in_sizes, int n_in,
                              void* d_out, int out_size, void* d_ws,
                              size_t ws_size, hipStream_t stream) {
  const float* x   = (const float*)d_in[0];
  const int* edge  = (const int*)d_in[1];
  const int* batch = (const int*)d_in[2];
  const float* w1l = (const float*)d_in[3];
  const float* b1l = (const float*)d_in[4];
  const float* w1r = (const float*)d_in[5];
  const float* w2l = (const float*)d_in[6];
  const float* b2l = (const float*)d_in[7];
  const float* w2r = (const float*)d_in[8];
  const float* wfc = (const float*)d_in[9];
  const float* bfc = (const float*)d_in[10];
  float* out = (float*)d_out;

  const int* src = edge;
  const int* dst = edge + NE;

  const size_t NF = (size_t)NN * 64;
  // zeroed region (contiguous): cnt[NN] + poolA + poolB + poolCnt
  int*   cnt     = (int*)d_ws;
  float* poolA   = (float*)(cnt + NN);
  float* poolB   = poolA + (size_t)NG * 64;
  float* poolCnt = poolB + (size_t)NG * 64;
  int*   cursor  = (int*)(poolCnt + NG);
  int*   rowptr  = cursor + NN;            // [NN+1] padded to 50004
  int*   bsum    = rowptr + 50004;         // [256]
  int*   ssrc    = bsum + 256;             // [NE]
  short* xwl     = (short*)(ssrc + NE);    // bf16 [NN][64]
  short* h1s     = xwl + NF;               // bf16 [NN][64]
  short* wbtf    = h1s + NF;               // bf16 frag-major [128][512]
  float* xwr     = (float*)(wbtf + 65536); // f32  [NN][64]
  float* agg2    = xwr + NF;               // f32  [NN][64]

  hipMemsetAsync(cnt, 0, (NN + 2 * NG * 64 + NG) * sizeof(int), stream);

  hist_kernel<<<(NE / 4 + 255) / 256, 256, 0, stream>>>(dst, cnt);
  scan1_kernel<<<SCAN_BLOCKS, 256, 0, stream>>>(cnt, rowptr, bsum);
  scan23_kernel<<<SCAN_BLOCKS, 256, 0, stream>>>(bsum, rowptr, cursor);
  scatter_kernel<<<(NE / 4 + 255) / 256, 256, 0, stream>>>(src, dst, cursor, ssrc);

  wbtf_prep_kernel<<<32, 256, 0, stream>>>(w1l, w1r, wbtf);
  gemm1_kernel<<<(NRT + 3) / 4, 256, 0, stream>>>(x, wbtf, xwl, xwr);

  agg1_h1_kernel<<<(NN + 3) / 4, 256, 0, stream>>>(rowptr, ssrc, xwl, xwr, b1l, h1s);
  agg2_kernel<<<(NN + 3) / 4, 256, 0, stream>>>(rowptr, ssrc, h1s, agg2);
  pool1_kernel<<<SCAN_BLOCKS, 256, 0, stream>>>(batch, agg2, h1s, rowptr, poolA, poolB, poolCnt);
  final_kernel<<<NG, 128, 0, stream>>>(poolA, poolB, poolCnt, w2l, w2r, b2l, wfc, bfc, out);
}

// Round 10
// 362.651 us; speedup vs baseline: 1.1417x; 1.0506x over previous
//
#include <hip/hip_runtime.h>

#define NN 50000      // nodes
#define NE 800000     // edges
#define FIN 512
#define H1DIM 64
#define H2DIM 128
#define NC 10
#define NG 64
#define NRT 3125      // NN/16 row-tiles
#define SCAN_BLOCKS 196   // ceil(50000/256)

typedef __attribute__((ext_vector_type(8))) short bf16x8;  // 8 bf16 (4 VGPRs)
typedef __attribute__((ext_vector_type(4))) float f32x4;

__device__ inline short f2bf(float f) {
  unsigned u = __float_as_uint(f);
  unsigned r = u + 0x7fffu + ((u >> 16) & 1u);  // RNE
  return (short)(r >> 16);
}
__device__ inline short f2bf_fast(float f) {   // round-half-up (2 VALU)
  return (short)((__float_as_uint(f) + 0x8000u) >> 16);
}
__device__ inline float bf2f(short s) {
  return __uint_as_float(((unsigned)(unsigned short)s) << 16);
}

// ---------------------------------------------------------------------------
// counting sort, split chain (max parallelism on heavy phases)
// ---------------------------------------------------------------------------
__global__ __launch_bounds__(256) void hist_kernel(const int* __restrict__ dst,
                                                   int* __restrict__ cnt) {
  int i = (blockIdx.x * 256 + threadIdx.x) * 4;
  if (i < NE) {
    int4 d = *(const int4*)(dst + i);
    atomicAdd(&cnt[d.x], 1);
    atomicAdd(&cnt[d.y], 1);
    atomicAdd(&cnt[d.z], 1);
    atomicAdd(&cnt[d.w], 1);
  }
}

__global__ __launch_bounds__(256) void scan1_kernel(const int* __restrict__ cnt,
                                                    int* __restrict__ excl,
                                                    int* __restrict__ bsum) {
  __shared__ int s[256];
  int t = threadIdx.x;
  int i = blockIdx.x * 256 + t;
  int v = (i < NN) ? cnt[i] : 0;
  s[t] = v;
  __syncthreads();
  for (int off = 1; off < 256; off <<= 1) {
    int u = (t >= off) ? s[t - off] : 0;
    __syncthreads();
    s[t] += u;
    __syncthreads();
  }
  if (i < NN) excl[i] = s[t] - v;       // exclusive within block
  if (t == 255) bsum[blockIdx.x] = s[255];
}

__global__ __launch_bounds__(256) void scan23_kernel(const int* __restrict__ bsum,
                                                     int* __restrict__ rowptr,
                                                     int* __restrict__ cursor) {
  __shared__ int s[256];
  int t = threadIdx.x;
  int b = blockIdx.x;
  int v = (t < SCAN_BLOCKS) ? bsum[t] : 0;
  s[t] = v;
  __syncthreads();
  for (int off = 1; off < 256; off <<= 1) {
    int u = (t >= off) ? s[t - off] : 0;
    __syncthreads();
    s[t] += u;
    __syncthreads();
  }
  int prefix = (b == 0) ? 0 : s[b - 1];
  int i = b * 256 + t;
  if (i < NN) {
    int p = rowptr[i] + prefix;
    rowptr[i] = p;
    cursor[i] = p;
  }
  if (i == 0) rowptr[NN] = NE;
}

__global__ __launch_bounds__(256) void scatter_kernel(
    const int* __restrict__ src, const int* __restrict__ dst,
    int* __restrict__ cursor, int* __restrict__ ssrc) {
  int i = (blockIdx.x * 256 + threadIdx.x) * 4;
  if (i < NE) {
    int4 s = *(const int4*)(src + i);
    int4 d = *(const int4*)(dst + i);
    int p0 = atomicAdd(&cursor[d.x], 1); ssrc[p0] = s.x;
    int p1 = atomicAdd(&cursor[d.y], 1); ssrc[p1] = s.y;
    int p2 = atomicAdd(&cursor[d.z], 1); ssrc[p2] = s.z;
    int p3 = atomicAdd(&cursor[d.w], 1); ssrc[p3] = s.w;
  }
}

// ---------------------------------------------------------------------------
// wbtf: [w1_l | w1_r] -> bf16 B-frag order.  131 KB, L2-resident.
// layout: shorts[((ni*16 + ks)*64 + lane)*8 + j]
// ---------------------------------------------------------------------------
__global__ __launch_bounds__(256) void wbtf_prep_kernel(
    const float* __restrict__ wl, const float* __restrict__ wr,
    short* __restrict__ wbtf) {
  int w = blockIdx.x * 4 + (threadIdx.x >> 6);   // 0..127 = ni*16+ks
  int lane = threadIdx.x & 63;
  int ni = w >> 4;
  int ks = w & 15;
  int n = ni * 16 + (lane & 15);
  int k = ks * 32 + (lane >> 4) * 8;
  bf16x8 o;
#pragma unroll
  for (int j = 0; j < 8; j++) {
    float v = (n < 64) ? wl[(size_t)(k + j) * 64 + n]
                       : wr[(size_t)(k + j) * 64 + (n - 64)];
    o[j] = f2bf(v);
  }
  *(bf16x8*)(wbtf + ((size_t)w * 64 + lane) * 8) = o;
}

// ---------------------------------------------------------------------------
// GEMM1 v10: B staged in 64 KB LDS per BLOCK (2 K-halves, 2 barriers total),
// A loaded direct from x (f32) with a depth-4 register ring, cvt in-register.
// Block = 4 waves x (16 rows x 128 cols). Kills the per-wave 128 KB B stream
// through L1/L2 that made r9 latency-bound.
// ---------------------------------------------------------------------------
__global__ __launch_bounds__(256) void gemm1_kernel(
    const float* __restrict__ x, const short* __restrict__ wbtf,
    short* __restrict__ xwl, float* __restrict__ xwr) {
  __shared__ short Bs[32768];   // 64 KB: 8 ni x 8 ksl x 64 lanes x 8 shorts

  const int t = threadIdx.x;
  const int w = blockIdx.x * 4 + (t >> 6);
  const int wc = (w < NRT) ? w : (NRT - 1);   // clamp; dup writes are identical
  const int lane = t & 63;
  const int l15 = lane & 15;
  const int q = lane >> 4;
  const float* px = x + (size_t)(wc * 16 + l15) * FIN + q * 8;  // + ks*32

  const f32x4 z = {0.f, 0.f, 0.f, 0.f};
  f32x4 acc[8];
#pragma unroll
  for (int ni = 0; ni < 8; ni++) acc[ni] = z;

  // A ring, depth 4
  float4 ra0[4], ra1[4];
#pragma unroll
  for (int i = 0; i < 4; i++) {
    ra0[i] = *(const float4*)(px + i * 32);
    ra1[i] = *(const float4*)(px + i * 32 + 4);
  }

#pragma unroll
  for (int h = 0; h < 2; h++) {
    // stage K-half h of wbtf into LDS: 4096 chunks of 16 B, 16 per thread
    if (h > 0) __syncthreads();   // all readers done with previous half
#pragma unroll
    for (int i = 0; i < 16; i++) {
      int c = i * 256 + t;          // 0..4095
      int ni = c >> 9;              // 512 chunks per ni
      int rem = c & 511;            // ksl*64 + lane
      ((bf16x8*)Bs)[c] =
          *(const bf16x8*)(wbtf + (size_t)ni * 8192 + h * 4096 + rem * 8);
    }
    __syncthreads();

#pragma unroll
    for (int ksl = 0; ksl < 8; ksl++) {
      int ks = h * 8 + ksl;
      int slot = ks & 3;
      bf16x8 af;
      {
        float4 v0 = ra0[slot], v1 = ra1[slot];
        af[0] = f2bf_fast(v0.x); af[1] = f2bf_fast(v0.y);
        af[2] = f2bf_fast(v0.z); af[3] = f2bf_fast(v0.w);
        af[4] = f2bf_fast(v1.x); af[5] = f2bf_fast(v1.y);
        af[6] = f2bf_fast(v1.z); af[7] = f2bf_fast(v1.w);
      }
      if (ks + 4 < 16) {
        ra0[slot] = *(const float4*)(px + (ks + 4) * 32);
        ra1[slot] = *(const float4*)(px + (ks + 4) * 32 + 4);
      }
#pragma unroll
      for (int ni = 0; ni < 8; ni++) {
        bf16x8 bf = *(const bf16x8*)(&Bs[((ni * 8 + ksl) * 64 + lane) * 8]);
        acc[ni] = __builtin_amdgcn_mfma_f32_16x16x32_bf16(af, bf, acc[ni], 0, 0, 0);
      }
    }
  }

  // epilogue: col = ni*16 + l15; row = wc*16 + q*4 + r
  int row_base = wc * 16 + q * 4;
#pragma unroll
  for (int ni = 0; ni < 8; ni++) {
    int col = ni * 16 + l15;
    int c = col & 63;
#pragma unroll
    for (int r = 0; r < 4; r++) {
      int row = row_base + r;
      if (col < 64) xwl[(size_t)row * 64 + c] = f2bf(acc[ni][r]);
      else          xwr[(size_t)row * 64 + c] = acc[ni][r];
    }
  }
}

// ---------------------------------------------------------------------------
// agg1 + h1: h1[i] = relu(mean_{s in N(i)} xwl[s] + b1 + xwr[i])  (bf16 out)
// ---------------------------------------------------------------------------
__global__ __launch_bounds__(256) void agg1_h1_kernel(
    const int* __restrict__ rowptr, const int* __restrict__ ssrc,
    const short* __restrict__ xwl, const float* __restrict__ xwr,
    const float* __restrict__ b1, short* __restrict__ h1) {
  int node = blockIdx.x * 4 + (threadIdx.x >> 6);
  if (node >= NN) return;
  int lane = threadIdx.x & 63;
  int c = lane & 7;        // feature chunk (8 bf16 = 16 B)
  int r = lane >> 3;       // edge slot 0..7
  int lo = rowptr[node], hi = rowptr[node + 1];
  float acc[8];
#pragma unroll
  for (int k = 0; k < 8; k++) acc[k] = 0.f;
  for (int e = lo + r; e < hi; e += 8) {
    int s = ssrc[e];
    bf16x8 v = *(const bf16x8*)(xwl + (size_t)s * 64 + c * 8);
#pragma unroll
    for (int k = 0; k < 8; k++) acc[k] += bf2f(v[k]);
  }
#pragma unroll
  for (int k = 0; k < 8; k++) {
    acc[k] += __shfl_xor(acc[k], 8);
    acc[k] += __shfl_xor(acc[k], 16);
    acc[k] += __shfl_xor(acc[k], 32);
  }
  if (r == 0) {
    float dg = fmaxf((float)(hi - lo), 1.0f);
    const float* xr = xwr + (size_t)node * 64 + c * 8;
    bf16x8 out;
#pragma unroll
    for (int k = 0; k < 8; k++) {
      float v = fmaxf(acc[k] / dg + b1[c * 8 + k] + xr[k], 0.f);
      out[k] = f2bf(v);
    }
    *(bf16x8*)(h1 + (size_t)node * 64 + c * 8) = out;
  }
}

// ---------------------------------------------------------------------------
// agg2: agg2[i] = sum_{s in N(i)} h1[s]   (f32 out, per-node — NO atomics)
// ---------------------------------------------------------------------------
__global__ __launch_bounds__(256) void agg2_kernel(
    const int* __restrict__ rowptr, const int* __restrict__ ssrc,
    const short* __restrict__ h1, float* __restrict__ agg2) {
  int node = blockIdx.x * 4 + (threadIdx.x >> 6);
  if (node >= NN) return;
  int lane = threadIdx.x & 63;
  int c = lane & 7;
  int r = lane >> 3;
  int lo = rowptr[node], hi = rowptr[node + 1];
  float acc[8];
#pragma unroll
  for (int k = 0; k < 8; k++) acc[k] = 0.f;
  for (int e = lo + r; e < hi; e += 8) {
    int s = ssrc[e];
    bf16x8 v = *(const bf16x8*)(h1 + (size_t)s * 64 + c * 8);
#pragma unroll
    for (int k = 0; k < 8; k++) acc[k] += bf2f(v[k]);
  }
#pragma unroll
  for (int k = 0; k < 8; k++) {
    acc[k] += __shfl_xor(acc[k], 8);
    acc[k] += __shfl_xor(acc[k], 16);
    acc[k] += __shfl_xor(acc[k], 32);
  }
  if (r == 0) {
    float* p = agg2 + (size_t)node * 64 + c * 8;
    f32x4 lo4 = {acc[0], acc[1], acc[2], acc[3]};
    f32x4 hi4 = {acc[4], acc[5], acc[6], acc[7]};
    *(f32x4*)(p) = lo4;
    *(f32x4*)(p + 4) = hi4;
  }
}

// ---------------------------------------------------------------------------
// pool phase1: run-length accumulate (batch sorted) + sparse atomic flush
// ---------------------------------------------------------------------------
__global__ __launch_bounds__(256) void pool1_kernel(
    const int* __restrict__ batch, const float* __restrict__ agg2,
    const short* __restrict__ h1, const int* __restrict__ rowptr,
    float* __restrict__ poolA, float* __restrict__ poolB,
    float* __restrict__ poolCnt) {
  int t = threadIdx.x;
  int c = t & 15;
  int s = t >> 4;
  int n0 = blockIdx.x * 256 + s * 16;
  int n1 = n0 + 16;
  if (n1 > NN) n1 = NN;

  f32x4 aA = {0.f, 0.f, 0.f, 0.f};
  f32x4 aB = {0.f, 0.f, 0.f, 0.f};
  int cur_g = -1;
  float run = 0.f;
  for (int n = n0; n < n1; n++) {
    int g = batch[n];
    if (g != cur_g) {
      if (cur_g >= 0) {
        float* pa = poolA + (size_t)cur_g * 64 + c * 4;
        float* pb = poolB + (size_t)cur_g * 64 + c * 4;
#pragma unroll
        for (int k = 0; k < 4; k++) {
          atomicAdd(&pa[k], aA[k]);
          atomicAdd(&pb[k], aB[k]);
        }
        if (c == 0) atomicAdd(&poolCnt[cur_g], run);
      }
      cur_g = g;
      aA = (f32x4){0.f, 0.f, 0.f, 0.f};
      aB = (f32x4){0.f, 0.f, 0.f, 0.f};
      run = 0.f;
    }
    float rd = 1.0f / fmaxf((float)(rowptr[n + 1] - rowptr[n]), 1.0f);
    f32x4 a2 = *(const f32x4*)(agg2 + (size_t)n * 64 + c * 4);
    const short* hp = h1 + (size_t)n * 64 + c * 4;
#pragma unroll
    for (int k = 0; k < 4; k++) {
      aA[k] = fmaf(a2[k], rd, aA[k]);
      aB[k] += bf2f(hp[k]);
    }
    run += 1.f;
  }
  if (cur_g >= 0) {
    float* pa = poolA + (size_t)cur_g * 64 + c * 4;
    float* pb = poolB + (size_t)cur_g * 64 + c * 4;
#pragma unroll
    for (int k = 0; k < 4; k++) {
      atomicAdd(&pa[k], aA[k]);
      atomicAdd(&pb[k], aB[k]);
    }
    if (c == 0) atomicAdd(&poolCnt[cur_g], run);
  }
}

// ---------------------------------------------------------------------------
// final: pooled = (poolA/cnt)@w2l + (poolB/cnt)@w2r + b2 ; @wfc + bfc ;
// log_softmax. One block per graph.
// ---------------------------------------------------------------------------
__global__ __launch_bounds__(128) void final_kernel(
    const float* __restrict__ poolA, const float* __restrict__ poolB,
    const float* __restrict__ poolCnt, const float* __restrict__ w2l,
    const float* __restrict__ w2r, const float* __restrict__ b2,
    const float* __restrict__ wfc, const float* __restrict__ bfc,
    float* __restrict__ out) {
  int g = blockIdx.x;
  int j = threadIdx.x;
  __shared__ float sp[H2DIM];
  __shared__ float sl[NC];

  float invc = 1.0f / fmaxf(poolCnt[g], 1.0f);
  float v = b2[j];
  for (int k = 0; k < 64; k++) {
    float a = poolA[g * 64 + k] * invc;
    float b = poolB[g * 64 + k] * invc;
    v = fmaf(a, w2l[k * 128 + j], v);
    v = fmaf(b, w2r[k * 128 + j], v);
  }
  sp[j] = v;
  __syncthreads();
  if (j < NC) {
    float lg = bfc[j];
    for (int k = 0; k < H2DIM; k++) lg = fmaf(sp[k], wfc[k * NC + j], lg);
    sl[j] = lg;
  }
  __syncthreads();
  if (j < NC) {
    float m = -1e30f;
    for (int k = 0; k < NC; k++) m = fmaxf(m, sl[k]);
    float s = 0.f;
    for (int k = 0; k < NC; k++) s += expf(sl[k] - m);
    out[g * NC + j] = sl[j] - m - logf(s);
  }
}

extern "C" void kernel_launch(void* const* d_in, const int* in_sizes, int n_in,
                              void* d_out, int out_size, void* d_ws,
                              size_t ws_size, hipStream_t stream) {
  const float* x   = (const float*)d_in[0];
  const int* edge  = (const int*)d_in[1];
  const int* batch = (const int*)d_in[2];
  const float* w1l = (const float*)d_in[3];
  const float* b1l = (const float*)d_in[4];
  const float* w1r = (const float*)d_in[5];
  const float* w2l = (const float*)d_in[6];
  const float* b2l = (const float*)d_in[7];
  const float* w2r = (const float*)d_in[8];
  const float* wfc = (const float*)d_in[9];
  const float* bfc = (const float*)d_in[10];
  float* out = (float*)d_out;

  const int* src = edge;
  const int* dst = edge + NE;

  const size_t NF = (size_t)NN * 64;
  // zeroed region (contiguous): cnt[NN] + poolA + poolB + poolCnt
  int*   cnt     = (int*)d_ws;
  float* poolA   = (float*)(cnt + NN);
  float* poolB   = poolA + (size_t)NG * 64;
  float* poolCnt = poolB + (size_t)NG * 64;
  int*   cursor  = (int*)(poolCnt + NG);
  int*   rowptr  = cursor + NN;            // [NN+1] padded to 50004
  int*   bsum    = rowptr + 50004;         // [256]
  int*   ssrc    = bsum + 256;             // [NE]
  short* xwl     = (short*)(ssrc + NE);    // bf16 [NN][64]
  short* h1s     = xwl + NF;               // bf16 [NN][64]
  short* wbtf    = h1s + NF;               // bf16 frag-major [128][512]
  float* xwr     = (float*)(wbtf + 65536); // f32  [NN][64]
  float* agg2    = xwr + NF;               // f32  [NN][64]

  hipMemsetAsync(cnt, 0, (NN + 2 * NG * 64 + NG) * sizeof(int), stream);

  hist_kernel<<<(NE / 4 + 255) / 256, 256, 0, stream>>>(dst, cnt);
  scan1_kernel<<<SCAN_BLOCKS, 256, 0, stream>>>(cnt, rowptr, bsum);
  scan23_kernel<<<SCAN_BLOCKS, 256, 0, stream>>>(bsum, rowptr, cursor);
  scatter_kernel<<<(NE / 4 + 255) / 256, 256, 0, stream>>>(src, dst, cursor, ssrc);

  wbtf_prep_kernel<<<32, 256, 0, stream>>>(w1l, w1r, wbtf);
  gemm1_kernel<<<(NRT + 3) / 4, 256, 0, stream>>>(x, wbtf, xwl, xwr);

  agg1_h1_kernel<<<(NN + 3) / 4, 256, 0, stream>>>(rowptr, ssrc, xwl, xwr, b1l, h1s);
  agg2_kernel<<<(NN + 3) / 4, 256, 0, stream>>>(rowptr, ssrc, h1s, agg2);
  pool1_kernel<<<SCAN_BLOCKS, 256, 0, stream>>>(batch, agg2, h1s, rowptr, poolA, poolB, poolCnt);
  final_kernel<<<NG, 128, 0, stream>>>(poolA, poolB, poolCnt, w2l, w2r, b2l, wfc, bfc, out);
}

// Round 11
// 351.287 us; speedup vs baseline: 1.1786x; 1.0324x over previous
//
#include <hip/hip_runtime.h>

#define NN 50000      // nodes
#define NE 800000     // edges
#define FIN 512
#define H1DIM 64
#define H2DIM 128
#define NC 10
#define NG 64
#define NRT 3125      // NN/16 row-tiles
#define SCAN_BLOCKS 196   // ceil(50000/256)
#define SLICES 8
#define SLICE_NODES (NN / SLICES)        // 6250
#define SCAT_GRPS 98                     // blocks per slice
#define SCAT_BLOCKS (SLICES * SCAT_GRPS) // 784

typedef __attribute__((ext_vector_type(8))) short bf16x8;  // 8 bf16 (4 VGPRs)
typedef __attribute__((ext_vector_type(4))) float f32x4;

__device__ inline short f2bf(float f) {
  unsigned u = __float_as_uint(f);
  unsigned r = u + 0x7fffu + ((u >> 16) & 1u);  // RNE
  return (short)(r >> 16);
}
__device__ inline short f2bf_fast(float f) {   // round-half-up (2 VALU)
  return (short)((__float_as_uint(f) + 0x8000u) >> 16);
}
__device__ inline float bf2f(short s) {
  return __uint_as_float(((unsigned)(unsigned short)s) << 16);
}

// ---------------------------------------------------------------------------
// counting sort, split chain
// ---------------------------------------------------------------------------
__global__ __launch_bounds__(256) void hist_kernel(const int* __restrict__ dst,
                                                   int* __restrict__ cnt) {
  int i = (blockIdx.x * 256 + threadIdx.x) * 4;
  if (i < NE) {
    int4 d = *(const int4*)(dst + i);
    atomicAdd(&cnt[d.x], 1);
    atomicAdd(&cnt[d.y], 1);
    atomicAdd(&cnt[d.z], 1);
    atomicAdd(&cnt[d.w], 1);
  }
}

__global__ __launch_bounds__(256) void scan1_kernel(const int* __restrict__ cnt,
                                                    int* __restrict__ excl,
                                                    int* __restrict__ bsum) {
  __shared__ int s[256];
  int t = threadIdx.x;
  int i = blockIdx.x * 256 + t;
  int v = (i < NN) ? cnt[i] : 0;
  s[t] = v;
  __syncthreads();
  for (int off = 1; off < 256; off <<= 1) {
    int u = (t >= off) ? s[t - off] : 0;
    __syncthreads();
    s[t] += u;
    __syncthreads();
  }
  if (i < NN) excl[i] = s[t] - v;       // exclusive within block
  if (t == 255) bsum[blockIdx.x] = s[255];
}

__global__ __launch_bounds__(256) void scan23_kernel(const int* __restrict__ bsum,
                                                     int* __restrict__ rowptr,
                                                     int* __restrict__ cursor) {
  __shared__ int s[256];
  int t = threadIdx.x;
  int b = blockIdx.x;
  int v = (t < SCAN_BLOCKS) ? bsum[t] : 0;
  s[t] = v;
  __syncthreads();
  for (int off = 1; off < 256; off <<= 1) {
    int u = (t >= off) ? s[t - off] : 0;
    __syncthreads();
    s[t] += u;
    __syncthreads();
  }
  int prefix = (b == 0) ? 0 : s[b - 1];
  int i = b * 256 + t;
  if (i < NN) {
    int p = rowptr[i] + prefix;
    rowptr[i] = p;
    cursor[i] = p;
  }
  if (i == 0) rowptr[NN] = NE;
}

// XCD-sliced scatter: blocks with (blockIdx&7)==p handle only dst in slice p,
// so each slice's ssrc region + cursor slice stay in ONE XCD's L2 ->
// write-amplification 16x -> ~1x. Edge list re-read 8x (L2/L3-resident).
__global__ __launch_bounds__(256) void scatter_kernel(
    const int* __restrict__ src, const int* __restrict__ dst,
    int* __restrict__ cursor, int* __restrict__ ssrc) {
  int slice = blockIdx.x & 7;
  int lo = slice * SLICE_NODES;
  int hi = lo + SLICE_NODES;
  int tid = (blockIdx.x >> 3) * 256 + threadIdx.x;   // 0..25087
  for (int j = tid; j < NE / 4; j += SCAT_GRPS * 256) {
    int4 s = *(const int4*)(src + j * 4);
    int4 d = *(const int4*)(dst + j * 4);
    if (d.x >= lo && d.x < hi) { int p = atomicAdd(&cursor[d.x], 1); ssrc[p] = s.x; }
    if (d.y >= lo && d.y < hi) { int p = atomicAdd(&cursor[d.y], 1); ssrc[p] = s.y; }
    if (d.z >= lo && d.z < hi) { int p = atomicAdd(&cursor[d.z], 1); ssrc[p] = s.z; }
    if (d.w >= lo && d.w < hi) { int p = atomicAdd(&cursor[d.w], 1); ssrc[p] = s.w; }
  }
}

// ---------------------------------------------------------------------------
// wbtf: [w1_l | w1_r] -> bf16 B-frag order.  131 KB, L2-resident.
// ---------------------------------------------------------------------------
__global__ __launch_bounds__(256) void wbtf_prep_kernel(
    const float* __restrict__ wl, const float* __restrict__ wr,
    short* __restrict__ wbtf) {
  int w = blockIdx.x * 4 + (threadIdx.x >> 6);   // 0..127 = ni*16+ks
  int lane = threadIdx.x & 63;
  int ni = w >> 4;
  int ks = w & 15;
  int n = ni * 16 + (lane & 15);
  int k = ks * 32 + (lane >> 4) * 8;
  bf16x8 o;
#pragma unroll
  for (int j = 0; j < 8; j++) {
    float v = (n < 64) ? wl[(size_t)(k + j) * 64 + n]
                       : wr[(size_t)(k + j) * 64 + (n - 64)];
    o[j] = f2bf(v);
  }
  *(bf16x8*)(wbtf + ((size_t)w * 64 + lane) * 8) = o;
}

// ---------------------------------------------------------------------------
// GEMM1: B staged in 64 KB LDS per block (2 K-halves, 2 barriers total),
// A direct from x (f32) with depth-4 register ring, cvt in-register.
// ---------------------------------------------------------------------------
__global__ __launch_bounds__(256) void gemm1_kernel(
    const float* __restrict__ x, const short* __restrict__ wbtf,
    short* __restrict__ xwl, float* __restrict__ xwr) {
  __shared__ short Bs[32768];   // 64 KB: 8 ni x 8 ksl x 64 lanes x 8 shorts

  const int t = threadIdx.x;
  const int w = blockIdx.x * 4 + (t >> 6);
  const int wc = (w < NRT) ? w : (NRT - 1);   // clamp; dup writes are identical
  const int lane = t & 63;
  const int l15 = lane & 15;
  const int q = lane >> 4;
  const float* px = x + (size_t)(wc * 16 + l15) * FIN + q * 8;  // + ks*32

  const f32x4 z = {0.f, 0.f, 0.f, 0.f};
  f32x4 acc[8];
#pragma unroll
  for (int ni = 0; ni < 8; ni++) acc[ni] = z;

  float4 ra0[4], ra1[4];
#pragma unroll
  for (int i = 0; i < 4; i++) {
    ra0[i] = *(const float4*)(px + i * 32);
    ra1[i] = *(const float4*)(px + i * 32 + 4);
  }

#pragma unroll
  for (int h = 0; h < 2; h++) {
    if (h > 0) __syncthreads();
#pragma unroll
    for (int i = 0; i < 16; i++) {
      int c = i * 256 + t;          // 0..4095
      int ni = c >> 9;
      int rem = c & 511;
      ((bf16x8*)Bs)[c] =
          *(const bf16x8*)(wbtf + (size_t)ni * 8192 + h * 4096 + rem * 8);
    }
    __syncthreads();

#pragma unroll
    for (int ksl = 0; ksl < 8; ksl++) {
      int ks = h * 8 + ksl;
      int slot = ks & 3;
      bf16x8 af;
      {
        float4 v0 = ra0[slot], v1 = ra1[slot];
        af[0] = f2bf_fast(v0.x); af[1] = f2bf_fast(v0.y);
        af[2] = f2bf_fast(v0.z); af[3] = f2bf_fast(v0.w);
        af[4] = f2bf_fast(v1.x); af[5] = f2bf_fast(v1.y);
        af[6] = f2bf_fast(v1.z); af[7] = f2bf_fast(v1.w);
      }
      if (ks + 4 < 16) {
        ra0[slot] = *(const float4*)(px + (ks + 4) * 32);
        ra1[slot] = *(const float4*)(px + (ks + 4) * 32 + 4);
      }
#pragma unroll
      for (int ni = 0; ni < 8; ni++) {
        bf16x8 bf = *(const bf16x8*)(&Bs[((ni * 8 + ksl) * 64 + lane) * 8]);
        acc[ni] = __builtin_amdgcn_mfma_f32_16x16x32_bf16(af, bf, acc[ni], 0, 0, 0);
      }
    }
  }

  int row_base = wc * 16 + q * 4;
#pragma unroll
  for (int ni = 0; ni < 8; ni++) {
    int col = ni * 16 + l15;
    int c = col & 63;
#pragma unroll
    for (int r = 0; r < 4; r++) {
      int row = row_base + r;
      if (col < 64) xwl[(size_t)row * 64 + c] = f2bf(acc[ni][r]);
      else          xwr[(size_t)row * 64 + c] = acc[ni][r];
    }
  }
}

// ---------------------------------------------------------------------------
// agg1 + h1: h1[i] = relu(mean_{s in N(i)} xwl[s] + b1 + xwr[i])  (bf16 out)
// ---------------------------------------------------------------------------
__global__ __launch_bounds__(256) void agg1_h1_kernel(
    const int* __restrict__ rowptr, const int* __restrict__ ssrc,
    const short* __restrict__ xwl, const float* __restrict__ xwr,
    const float* __restrict__ b1, short* __restrict__ h1) {
  int node = blockIdx.x * 4 + (threadIdx.x >> 6);
  if (node >= NN) return;
  int lane = threadIdx.x & 63;
  int c = lane & 7;        // feature chunk (8 bf16 = 16 B)
  int r = lane >> 3;       // edge slot 0..7
  int lo = rowptr[node], hi = rowptr[node + 1];
  float acc[8];
#pragma unroll
  for (int k = 0; k < 8; k++) acc[k] = 0.f;
  for (int e = lo + r; e < hi; e += 8) {
    int s = ssrc[e];
    bf16x8 v = *(const bf16x8*)(xwl + (size_t)s * 64 + c * 8);
#pragma unroll
    for (int k = 0; k < 8; k++) acc[k] += bf2f(v[k]);
  }
#pragma unroll
  for (int k = 0; k < 8; k++) {
    acc[k] += __shfl_xor(acc[k], 8);
    acc[k] += __shfl_xor(acc[k], 16);
    acc[k] += __shfl_xor(acc[k], 32);
  }
  if (r == 0) {
    float dg = fmaxf((float)(hi - lo), 1.0f);
    const float* xr = xwr + (size_t)node * 64 + c * 8;
    bf16x8 out;
#pragma unroll
    for (int k = 0; k < 8; k++) {
      float v = fmaxf(acc[k] / dg + b1[c * 8 + k] + xr[k], 0.f);
      out[k] = f2bf(v);
    }
    *(bf16x8*)(h1 + (size_t)node * 64 + c * 8) = out;
  }
}

// ---------------------------------------------------------------------------
// agg2: agg2[i] = sum_{s in N(i)} h1[s]   (f32 out, per-node — NO atomics)
// ---------------------------------------------------------------------------
__global__ __launch_bounds__(256) void agg2_kernel(
    const int* __restrict__ rowptr, const int* __restrict__ ssrc,
    const short* __restrict__ h1, float* __restrict__ agg2) {
  int node = blockIdx.x * 4 + (threadIdx.x >> 6);
  if (node >= NN) return;
  int lane = threadIdx.x & 63;
  int c = lane & 7;
  int r = lane >> 3;
  int lo = rowptr[node], hi = rowptr[node + 1];
  float acc[8];
#pragma unroll
  for (int k = 0; k < 8; k++) acc[k] = 0.f;
  for (int e = lo + r; e < hi; e += 8) {
    int s = ssrc[e];
    bf16x8 v = *(const bf16x8*)(h1 + (size_t)s * 64 + c * 8);
#pragma unroll
    for (int k = 0; k < 8; k++) acc[k] += bf2f(v[k]);
  }
#pragma unroll
  for (int k = 0; k < 8; k++) {
    acc[k] += __shfl_xor(acc[k], 8);
    acc[k] += __shfl_xor(acc[k], 16);
    acc[k] += __shfl_xor(acc[k], 32);
  }
  if (r == 0) {
    float* p = agg2 + (size_t)node * 64 + c * 8;
    f32x4 lo4 = {acc[0], acc[1], acc[2], acc[3]};
    f32x4 hi4 = {acc[4], acc[5], acc[6], acc[7]};
    *(f32x4*)(p) = lo4;
    *(f32x4*)(p + 4) = hi4;
  }
}

// ---------------------------------------------------------------------------
// pool phase1: run-length accumulate (batch sorted) + sparse atomic flush
// ---------------------------------------------------------------------------
__global__ __launch_bounds__(256) void pool1_kernel(
    const int* __restrict__ batch, const float* __restrict__ agg2,
    const short* __restrict__ h1, const int* __restrict__ rowptr,
    float* __restrict__ poolA, float* __restrict__ poolB,
    float* __restrict__ poolCnt) {
  int t = threadIdx.x;
  int c = t & 15;
  int s = t >> 4;
  int n0 = blockIdx.x * 256 + s * 16;
  int n1 = n0 + 16;
  if (n1 > NN) n1 = NN;

  f32x4 aA = {0.f, 0.f, 0.f, 0.f};
  f32x4 aB = {0.f, 0.f, 0.f, 0.f};
  int cur_g = -1;
  float run = 0.f;
  for (int n = n0; n < n1; n++) {
    int g = batch[n];
    if (g != cur_g) {
      if (cur_g >= 0) {
        float* pa = poolA + (size_t)cur_g * 64 + c * 4;
        float* pb = poolB + (size_t)cur_g * 64 + c * 4;
#pragma unroll
        for (int k = 0; k < 4; k++) {
          atomicAdd(&pa[k], aA[k]);
          atomicAdd(&pb[k], aB[k]);
        }
        if (c == 0) atomicAdd(&poolCnt[cur_g], run);
      }
      cur_g = g;
      aA = (f32x4){0.f, 0.f, 0.f, 0.f};
      aB = (f32x4){0.f, 0.f, 0.f, 0.f};
      run = 0.f;
    }
    float rd = 1.0f / fmaxf((float)(rowptr[n + 1] - rowptr[n]), 1.0f);
    f32x4 a2 = *(const f32x4*)(agg2 + (size_t)n * 64 + c * 4);
    const short* hp = h1 + (size_t)n * 64 + c * 4;
#pragma unroll
    for (int k = 0; k < 4; k++) {
      aA[k] = fmaf(a2[k], rd, aA[k]);
      aB[k] += bf2f(hp[k]);
    }
    run += 1.f;
  }
  if (cur_g >= 0) {
    float* pa = poolA + (size_t)cur_g * 64 + c * 4;
    float* pb = poolB + (size_t)cur_g * 64 + c * 4;
#pragma unroll
    for (int k = 0; k < 4; k++) {
      atomicAdd(&pa[k], aA[k]);
      atomicAdd(&pb[k], aB[k]);
    }
    if (c == 0) atomicAdd(&poolCnt[cur_g], run);
  }
}

// ---------------------------------------------------------------------------
// final: pooled = (poolA/cnt)@w2l + (poolB/cnt)@w2r + b2 ; @wfc + bfc ;
// log_softmax. One block per graph.
// ---------------------------------------------------------------------------
__global__ __launch_bounds__(128) void final_kernel(
    const float* __restrict__ poolA, const float* __restrict__ poolB,
    const float* __restrict__ poolCnt, const float* __restrict__ w2l,
    const float* __restrict__ w2r, const float* __restrict__ b2,
    const float* __restrict__ wfc, const float* __restrict__ bfc,
    float* __restrict__ out) {
  int g = blockIdx.x;
  int j = threadIdx.x;
  __shared__ float sp[H2DIM];
  __shared__ float sl[NC];

  float invc = 1.0f / fmaxf(poolCnt[g], 1.0f);
  float v = b2[j];
  for (int k = 0; k < 64; k++) {
    float a = poolA[g * 64 + k] * invc;
    float b = poolB[g * 64 + k] * invc;
    v = fmaf(a, w2l[k * 128 + j], v);
    v = fmaf(b, w2r[k * 128 + j], v);
  }
  sp[j] = v;
  __syncthreads();
  if (j < NC) {
    float lg = bfc[j];
    for (int k = 0; k < H2DIM; k++) lg = fmaf(sp[k], wfc[k * NC + j], lg);
    sl[j] = lg;
  }
  __syncthreads();
  if (j < NC) {
    float m = -1e30f;
    for (int k = 0; k < NC; k++) m = fmaxf(m, sl[k]);
    float s = 0.f;
    for (int k = 0; k < NC; k++) s += expf(sl[k] - m);
    out[g * NC + j] = sl[j] - m - logf(s);
  }
}

extern "C" void kernel_launch(void* const* d_in, const int* in_sizes, int n_in,
                              void* d_out, int out_size, void* d_ws,
                              size_t ws_size, hipStream_t stream) {
  const float* x   = (const float*)d_in[0];
  const int* edge  = (const int*)d_in[1];
  const int* batch = (const int*)d_in[2];
  const float* w1l = (const float*)d_in[3];
  const float* b1l = (const float*)d_in[4];
  const float* w1r = (const float*)d_in[5];
  const float* w2l = (const float*)d_in[6];
  const float* b2l = (const float*)d_in[7];
  const float* w2r = (const float*)d_in[8];
  const float* wfc = (const float*)d_in[9];
  const float* bfc = (const float*)d_in[10];
  float* out = (float*)d_out;

  const int* src = edge;
  const int* dst = edge + NE;

  const size_t NF = (size_t)NN * 64;
  // zeroed region (contiguous): cnt[NN] + poolA + poolB + poolCnt
  int*   cnt     = (int*)d_ws;
  float* poolA   = (float*)(cnt + NN);
  float* poolB   = poolA + (size_t)NG * 64;
  float* poolCnt = poolB + (size_t)NG * 64;
  int*   cursor  = (int*)(poolCnt + NG);
  int*   rowptr  = cursor + NN;            // [NN+1] padded to 50004
  int*   bsum    = rowptr + 50004;         // [256]
  int*   ssrc    = bsum + 256;             // [NE]
  short* xwl     = (short*)(ssrc + NE);    // bf16 [NN][64]
  short* h1s     = xwl + NF;               // bf16 [NN][64]
  short* wbtf    = h1s + NF;               // bf16 frag-major [128][512]
  float* xwr     = (float*)(wbtf + 65536); // f32  [NN][64]
  float* agg2    = xwr + NF;               // f32  [NN][64]

  hipMemsetAsync(cnt, 0, (NN + 2 * NG * 64 + NG) * sizeof(int), stream);

  hist_kernel<<<(NE / 4 + 255) / 256, 256, 0, stream>>>(dst, cnt);
  scan1_kernel<<<SCAN_BLOCKS, 256, 0, stream>>>(cnt, rowptr, bsum);
  scan23_kernel<<<SCAN_BLOCKS, 256, 0, stream>>>(bsum, rowptr, cursor);
  scatter_kernel<<<SCAT_BLOCKS, 256, 0, stream>>>(src, dst, cursor, ssrc);

  wbtf_prep_kernel<<<32, 256, 0, stream>>>(w1l, w1r, wbtf);
  gemm1_kernel<<<(NRT + 3) / 4, 256, 0, stream>>>(x, wbtf, xwl, xwr);

  agg1_h1_kernel<<<(NN + 3) / 4, 256, 0, stream>>>(rowptr, ssrc, xwl, xwr, b1l, h1s);
  agg2_kernel<<<(NN + 3) / 4, 256, 0, stream>>>(rowptr, ssrc, h1s, agg2);
  pool1_kernel<<<SCAN_BLOCKS, 256, 0, stream>>>(batch, agg2, h1s, rowptr, poolA, poolB, poolCnt);
  final_kernel<<<NG, 128, 0, stream>>>(poolA, poolB, poolCnt, w2l, w2r, b2l, wfc, bfc, out);
}

// Round 12
// 346.993 us; speedup vs baseline: 1.1932x; 1.0124x over previous
//
#include <hip/hip_runtime.h>

#define NN 50000      // nodes
#define NE 800000     // edges
#define FIN 512
#define H1DIM 64
#define H2DIM 128
#define NC 10
#define NG 64
#define NRT 3125      // NN/16 row-tiles
#define SCAN_BLOCKS 196   // ceil(50000/256)
#define SLICES 8
#define SLICE_NODES (NN / SLICES)        // 6250
#define SCAT_GRPS 98                     // blocks per slice
#define SCAT_BLOCKS (SLICES * SCAT_GRPS) // 784
#define HIST_BLOCKS 782                  // ceil(NE/4/256)
#define GEMM_BLOCKS 782                  // ceil(NRT/4)

typedef __attribute__((ext_vector_type(8))) short bf16x8;  // 8 bf16 (4 VGPRs)
typedef __attribute__((ext_vector_type(4))) float f32x4;

__device__ inline short f2bf(float f) {
  unsigned u = __float_as_uint(f);
  unsigned r = u + 0x7fffu + ((u >> 16) & 1u);  // RNE
  return (short)(r >> 16);
}
__device__ inline short f2bf_fast(float f) {   // round-half-up (2 VALU)
  return (short)((__float_as_uint(f) + 0x8000u) >> 16);
}
__device__ inline float bf2f(short s) {
  return __uint_as_float(((unsigned)(unsigned short)s) << 16);
}

// ---------------------------------------------------------------------------
// D1: hist (782 blks) ∪ wbtf prep (32 blks) — independent work, one dispatch
// ---------------------------------------------------------------------------
__global__ __launch_bounds__(256) void histwbtf_kernel(
    const int* __restrict__ dst, int* __restrict__ cnt,
    const float* __restrict__ wl, const float* __restrict__ wr,
    short* __restrict__ wbtf) {
  int b = blockIdx.x;
  if (b < HIST_BLOCKS) {
    int i = (b * 256 + threadIdx.x) * 4;
    if (i < NE) {
      int4 d = *(const int4*)(dst + i);
      atomicAdd(&cnt[d.x], 1);
      atomicAdd(&cnt[d.y], 1);
      atomicAdd(&cnt[d.z], 1);
      atomicAdd(&cnt[d.w], 1);
    }
  } else {
    int w = (b - HIST_BLOCKS) * 4 + (threadIdx.x >> 6);   // 0..127 = ni*16+ks
    int lane = threadIdx.x & 63;
    int ni = w >> 4;
    int ks = w & 15;
    int n = ni * 16 + (lane & 15);
    int k = ks * 32 + (lane >> 4) * 8;
    bf16x8 o;
#pragma unroll
    for (int j = 0; j < 8; j++) {
      float v = (n < 64) ? wl[(size_t)(k + j) * 64 + n]
                         : wr[(size_t)(k + j) * 64 + (n - 64)];
      o[j] = f2bf(v);
    }
    *(bf16x8*)(wbtf + ((size_t)w * 64 + lane) * 8) = o;
  }
}

__global__ __launch_bounds__(256) void scan1_kernel(const int* __restrict__ cnt,
                                                    int* __restrict__ excl,
                                                    int* __restrict__ bsum) {
  __shared__ int s[256];
  int t = threadIdx.x;
  int i = blockIdx.x * 256 + t;
  int v = (i < NN) ? cnt[i] : 0;
  s[t] = v;
  __syncthreads();
  for (int off = 1; off < 256; off <<= 1) {
    int u = (t >= off) ? s[t - off] : 0;
    __syncthreads();
    s[t] += u;
    __syncthreads();
  }
  if (i < NN) excl[i] = s[t] - v;       // exclusive within block
  if (t == 255) bsum[blockIdx.x] = s[255];
}

__global__ __launch_bounds__(256) void scan23_kernel(const int* __restrict__ bsum,
                                                     int* __restrict__ rowptr,
                                                     int* __restrict__ cursor) {
  __shared__ int s[256];
  int t = threadIdx.x;
  int b = blockIdx.x;
  int v = (t < SCAN_BLOCKS) ? bsum[t] : 0;
  s[t] = v;
  __syncthreads();
  for (int off = 1; off < 256; off <<= 1) {
    int u = (t >= off) ? s[t - off] : 0;
    __syncthreads();
    s[t] += u;
    __syncthreads();
  }
  int prefix = (b == 0) ? 0 : s[b - 1];
  int i = b * 256 + t;
  if (i < NN) {
    int p = rowptr[i] + prefix;
    rowptr[i] = p;
    cursor[i] = p;
  }
  if (i == 0) rowptr[NN] = NE;
}

// ---------------------------------------------------------------------------
// D4: XCD-sliced scatter (784 blks, blockIdx&7 slicing preserved) ∪
//     gemm1 (782 blks, 64KB-LDS B staging). Complementary pipes overlap.
// ---------------------------------------------------------------------------
__global__ __launch_bounds__(256) void scatgemm_kernel(
    const int* __restrict__ src, const int* __restrict__ dst,
    int* __restrict__ cursor, int* __restrict__ ssrc,
    const float* __restrict__ x, const short* __restrict__ wbtf,
    short* __restrict__ xwl, float* __restrict__ xwr) {
  __shared__ short Bs[32768];   // 64 KB (gemm blocks only)

  if (blockIdx.x < SCAT_BLOCKS) {
    // ---- scatter: slice by (blockIdx&7) for XCD L2 locality ----
    int slice = blockIdx.x & 7;
    int lo = slice * SLICE_NODES;
    int hi = lo + SLICE_NODES;
    int tid = (blockIdx.x >> 3) * 256 + threadIdx.x;   // 0..25087
    for (int j = tid; j < NE / 4; j += SCAT_GRPS * 256) {
      int4 s = *(const int4*)(src + j * 4);
      int4 d = *(const int4*)(dst + j * 4);
      if (d.x >= lo && d.x < hi) { int p = atomicAdd(&cursor[d.x], 1); ssrc[p] = s.x; }
      if (d.y >= lo && d.y < hi) { int p = atomicAdd(&cursor[d.y], 1); ssrc[p] = s.y; }
      if (d.z >= lo && d.z < hi) { int p = atomicAdd(&cursor[d.z], 1); ssrc[p] = s.z; }
      if (d.w >= lo && d.w < hi) { int p = atomicAdd(&cursor[d.w], 1); ssrc[p] = s.w; }
    }
    return;
  }

  // ---- gemm1 ----
  const int t = threadIdx.x;
  const int w = (blockIdx.x - SCAT_BLOCKS) * 4 + (t >> 6);
  const int wc = (w < NRT) ? w : (NRT - 1);   // clamp; dup writes identical
  const int lane = t & 63;
  const int l15 = lane & 15;
  const int q = lane >> 4;
  const float* px = x + (size_t)(wc * 16 + l15) * FIN + q * 8;  // + ks*32

  const f32x4 z = {0.f, 0.f, 0.f, 0.f};
  f32x4 acc[8];
#pragma unroll
  for (int ni = 0; ni < 8; ni++) acc[ni] = z;

  float4 ra0[4], ra1[4];
#pragma unroll
  for (int i = 0; i < 4; i++) {
    ra0[i] = *(const float4*)(px + i * 32);
    ra1[i] = *(const float4*)(px + i * 32 + 4);
  }

#pragma unroll
  for (int h = 0; h < 2; h++) {
    if (h > 0) __syncthreads();
#pragma unroll
    for (int i = 0; i < 16; i++) {
      int c = i * 256 + t;          // 0..4095
      int ni = c >> 9;
      int rem = c & 511;
      ((bf16x8*)Bs)[c] =
          *(const bf16x8*)(wbtf + (size_t)ni * 8192 + h * 4096 + rem * 8);
    }
    __syncthreads();

#pragma unroll
    for (int ksl = 0; ksl < 8; ksl++) {
      int ks = h * 8 + ksl;
      int slot = ks & 3;
      bf16x8 af;
      {
        float4 v0 = ra0[slot], v1 = ra1[slot];
        af[0] = f2bf_fast(v0.x); af[1] = f2bf_fast(v0.y);
        af[2] = f2bf_fast(v0.z); af[3] = f2bf_fast(v0.w);
        af[4] = f2bf_fast(v1.x); af[5] = f2bf_fast(v1.y);
        af[6] = f2bf_fast(v1.z); af[7] = f2bf_fast(v1.w);
      }
      if (ks + 4 < 16) {
        ra0[slot] = *(const float4*)(px + (ks + 4) * 32);
        ra1[slot] = *(const float4*)(px + (ks + 4) * 32 + 4);
      }
#pragma unroll
      for (int ni = 0; ni < 8; ni++) {
        bf16x8 bf = *(const bf16x8*)(&Bs[((ni * 8 + ksl) * 64 + lane) * 8]);
        acc[ni] = __builtin_amdgcn_mfma_f32_16x16x32_bf16(af, bf, acc[ni], 0, 0, 0);
      }
    }
  }

  int row_base = wc * 16 + q * 4;
#pragma unroll
  for (int ni = 0; ni < 8; ni++) {
    int col = ni * 16 + l15;
    int c = col & 63;
#pragma unroll
    for (int r = 0; r < 4; r++) {
      int row = row_base + r;
      if (col < 64) xwl[(size_t)row * 64 + c] = f2bf(acc[ni][r]);
      else          xwr[(size_t)row * 64 + c] = acc[ni][r];
    }
  }
}

// ---------------------------------------------------------------------------
// agg1 + h1: h1[i] = relu(mean_{s in N(i)} xwl[s] + b1 + xwr[i])  (bf16 out)
// ---------------------------------------------------------------------------
__global__ __launch_bounds__(256) void agg1_h1_kernel(
    const int* __restrict__ rowptr, const int* __restrict__ ssrc,
    const short* __restrict__ xwl, const float* __restrict__ xwr,
    const float* __restrict__ b1, short* __restrict__ h1) {
  int node = blockIdx.x * 4 + (threadIdx.x >> 6);
  if (node >= NN) return;
  int lane = threadIdx.x & 63;
  int c = lane & 7;        // feature chunk (8 bf16 = 16 B)
  int r = lane >> 3;       // edge slot 0..7
  int lo = rowptr[node], hi = rowptr[node + 1];
  float acc[8];
#pragma unroll
  for (int k = 0; k < 8; k++) acc[k] = 0.f;
  for (int e = lo + r; e < hi; e += 8) {
    int s = ssrc[e];
    bf16x8 v = *(const bf16x8*)(xwl + (size_t)s * 64 + c * 8);
#pragma unroll
    for (int k = 0; k < 8; k++) acc[k] += bf2f(v[k]);
  }
#pragma unroll
  for (int k = 0; k < 8; k++) {
    acc[k] += __shfl_xor(acc[k], 8);
    acc[k] += __shfl_xor(acc[k], 16);
    acc[k] += __shfl_xor(acc[k], 32);
  }
  if (r == 0) {
    float dg = fmaxf((float)(hi - lo), 1.0f);
    const float* xr = xwr + (size_t)node * 64 + c * 8;
    bf16x8 out;
#pragma unroll
    for (int k = 0; k < 8; k++) {
      float v = fmaxf(acc[k] / dg + b1[c * 8 + k] + xr[k], 0.f);
      out[k] = f2bf(v);
    }
    *(bf16x8*)(h1 + (size_t)node * 64 + c * 8) = out;
  }
}

// ---------------------------------------------------------------------------
// agg2: agg2[i] = sum_{s in N(i)} h1[s]   (f32 out, per-node — NO atomics)
// ---------------------------------------------------------------------------
__global__ __launch_bounds__(256) void agg2_kernel(
    const int* __restrict__ rowptr, const int* __restrict__ ssrc,
    const short* __restrict__ h1, float* __restrict__ agg2) {
  int node = blockIdx.x * 4 + (threadIdx.x >> 6);
  if (node >= NN) return;
  int lane = threadIdx.x & 63;
  int c = lane & 7;
  int r = lane >> 3;
  int lo = rowptr[node], hi = rowptr[node + 1];
  float acc[8];
#pragma unroll
  for (int k = 0; k < 8; k++) acc[k] = 0.f;
  for (int e = lo + r; e < hi; e += 8) {
    int s = ssrc[e];
    bf16x8 v = *(const bf16x8*)(h1 + (size_t)s * 64 + c * 8);
#pragma unroll
    for (int k = 0; k < 8; k++) acc[k] += bf2f(v[k]);
  }
#pragma unroll
  for (int k = 0; k < 8; k++) {
    acc[k] += __shfl_xor(acc[k], 8);
    acc[k] += __shfl_xor(acc[k], 16);
    acc[k] += __shfl_xor(acc[k], 32);
  }
  if (r == 0) {
    float* p = agg2 + (size_t)node * 64 + c * 8;
    f32x4 lo4 = {acc[0], acc[1], acc[2], acc[3]};
    f32x4 hi4 = {acc[4], acc[5], acc[6], acc[7]};
    *(f32x4*)(p) = lo4;
    *(f32x4*)(p + 4) = hi4;
  }
}

// ---------------------------------------------------------------------------
// pool phase1: run-length accumulate (batch sorted) + sparse atomic flush
// ---------------------------------------------------------------------------
__global__ __launch_bounds__(256) void pool1_kernel(
    const int* __restrict__ batch, const float* __restrict__ agg2,
    const short* __restrict__ h1, const int* __restrict__ rowptr,
    float* __restrict__ poolA, float* __restrict__ poolB,
    float* __restrict__ poolCnt) {
  int t = threadIdx.x;
  int c = t & 15;
  int s = t >> 4;
  int n0 = blockIdx.x * 256 + s * 16;
  int n1 = n0 + 16;
  if (n1 > NN) n1 = NN;

  f32x4 aA = {0.f, 0.f, 0.f, 0.f};
  f32x4 aB = {0.f, 0.f, 0.f, 0.f};
  int cur_g = -1;
  float run = 0.f;
  for (int n = n0; n < n1; n++) {
    int g = batch[n];
    if (g != cur_g) {
      if (cur_g >= 0) {
        float* pa = poolA + (size_t)cur_g * 64 + c * 4;
        float* pb = poolB + (size_t)cur_g * 64 + c * 4;
#pragma unroll
        for (int k = 0; k < 4; k++) {
          atomicAdd(&pa[k], aA[k]);
          atomicAdd(&pb[k], aB[k]);
        }
        if (c == 0) atomicAdd(&poolCnt[cur_g], run);
      }
      cur_g = g;
      aA = (f32x4){0.f, 0.f, 0.f, 0.f};
      aB = (f32x4){0.f, 0.f, 0.f, 0.f};
      run = 0.f;
    }
    float rd = 1.0f / fmaxf((float)(rowptr[n + 1] - rowptr[n]), 1.0f);
    f32x4 a2 = *(const f32x4*)(agg2 + (size_t)n * 64 + c * 4);
    const short* hp = h1 + (size_t)n * 64 + c * 4;
#pragma unroll
    for (int k = 0; k < 4; k++) {
      aA[k] = fmaf(a2[k], rd, aA[k]);
      aB[k] += bf2f(hp[k]);
    }
    run += 1.f;
  }
  if (cur_g >= 0) {
    float* pa = poolA + (size_t)cur_g * 64 + c * 4;
    float* pb = poolB + (size_t)cur_g * 64 + c * 4;
#pragma unroll
    for (int k = 0; k < 4; k++) {
      atomicAdd(&pa[k], aA[k]);
      atomicAdd(&pb[k], aB[k]);
    }
    if (c == 0) atomicAdd(&poolCnt[cur_g], run);
  }
}

// ---------------------------------------------------------------------------
// final: pooled = (poolA/cnt)@w2l + (poolB/cnt)@w2r + b2 ; @wfc + bfc ;
// log_softmax. One block per graph.
// ---------------------------------------------------------------------------
__global__ __launch_bounds__(128) void final_kernel(
    const float* __restrict__ poolA, const float* __restrict__ poolB,
    const float* __restrict__ poolCnt, const float* __restrict__ w2l,
    const float* __restrict__ w2r, const float* __restrict__ b2,
    const float* __restrict__ wfc, const float* __restrict__ bfc,
    float* __restrict__ out) {
  int g = blockIdx.x;
  int j = threadIdx.x;
  __shared__ float sp[H2DIM];
  __shared__ float sl[NC];

  float invc = 1.0f / fmaxf(poolCnt[g], 1.0f);
  float v = b2[j];
  for (int k = 0; k < 64; k++) {
    float a = poolA[g * 64 + k] * invc;
    float b = poolB[g * 64 + k] * invc;
    v = fmaf(a, w2l[k * 128 + j], v);
    v = fmaf(b, w2r[k * 128 + j], v);
  }
  sp[j] = v;
  __syncthreads();
  if (j < NC) {
    float lg = bfc[j];
    for (int k = 0; k < H2DIM; k++) lg = fmaf(sp[k], wfc[k * NC + j], lg);
    sl[j] = lg;
  }
  __syncthreads();
  if (j < NC) {
    float m = -1e30f;
    for (int k = 0; k < NC; k++) m = fmaxf(m, sl[k]);
    float s = 0.f;
    for (int k = 0; k < NC; k++) s += expf(sl[k] - m);
    out[g * NC + j] = sl[j] - m - logf(s);
  }
}

extern "C" void kernel_launch(void* const* d_in, const int* in_sizes, int n_in,
                              void* d_out, int out_size, void* d_ws,
                              size_t ws_size, hipStream_t stream) {
  const float* x   = (const float*)d_in[0];
  const int* edge  = (const int*)d_in[1];
  const int* batch = (const int*)d_in[2];
  const float* w1l = (const float*)d_in[3];
  const float* b1l = (const float*)d_in[4];
  const float* w1r = (const float*)d_in[5];
  const float* w2l = (const float*)d_in[6];
  const float* b2l = (const float*)d_in[7];
  const float* w2r = (const float*)d_in[8];
  const float* wfc = (const float*)d_in[9];
  const float* bfc = (const float*)d_in[10];
  float* out = (float*)d_out;

  const int* src = edge;
  const int* dst = edge + NE;

  const size_t NF = (size_t)NN * 64;
  // zeroed region (contiguous): cnt[NN] + poolA + poolB + poolCnt
  int*   cnt     = (int*)d_ws;
  float* poolA   = (float*)(cnt + NN);
  float* poolB   = poolA + (size_t)NG * 64;
  float* poolCnt = poolB + (size_t)NG * 64;
  int*   cursor  = (int*)(poolCnt + NG);
  int*   rowptr  = cursor + NN;            // [NN+1] padded to 50004
  int*   bsum    = rowptr + 50004;         // [256]
  int*   ssrc    = bsum + 256;             // [NE]
  short* xwl     = (short*)(ssrc + NE);    // bf16 [NN][64]
  short* h1s     = xwl + NF;               // bf16 [NN][64]
  short* wbtf    = h1s + NF;               // bf16 frag-major [128][512]
  float* xwr     = (float*)(wbtf + 65536); // f32  [NN][64]
  float* agg2    = xwr + NF;               // f32  [NN][64]

  hipMemsetAsync(cnt, 0, (NN + 2 * NG * 64 + NG) * sizeof(int), stream);

  histwbtf_kernel<<<HIST_BLOCKS + 32, 256, 0, stream>>>(dst, cnt, w1l, w1r, wbtf);
  scan1_kernel<<<SCAN_BLOCKS, 256, 0, stream>>>(cnt, rowptr, bsum);
  scan23_kernel<<<SCAN_BLOCKS, 256, 0, stream>>>(bsum, rowptr, cursor);
  scatgemm_kernel<<<SCAT_BLOCKS + GEMM_BLOCKS, 256, 0, stream>>>(
      src, dst, cursor, ssrc, x, wbtf, xwl, xwr);

  agg1_h1_kernel<<<(NN + 3) / 4, 256, 0, stream>>>(rowptr, ssrc, xwl, xwr, b1l, h1s);
  agg2_kernel<<<(NN + 3) / 4, 256, 0, stream>>>(rowptr, ssrc, h1s, agg2);
  pool1_kernel<<<SCAN_BLOCKS, 256, 0, stream>>>(batch, agg2, h1s, rowptr, poolA, poolB, poolCnt);
  final_kernel<<<NG, 128, 0, stream>>>(poolA, poolB, poolCnt, w2l, w2r, b2l, wfc, bfc, out);
}